// Round 7
// baseline (238.645 us; speedup 1.0000x reference)
//
#include <hip/hip_runtime.h>

// Attention over channel dim: B=16, HW=16384, C=64, fp32.
// scores[b,q,k] = sum_hw Q[b,hw,q]*K[b,hw,k]; attn=softmax_k; out[b,hw,q]=sum_k attn[b,q,k]*V[b,hw,k]
//
// ws: partial scores [B][SPLIT][64][64] fp32, then attn_t [B][64k][64q] fp32 (256 KB).
// SPLIT=64 (16 MiB) if ws allows, else 32 (8 MiB).
//
// Round-7: scores via MFMA (split-bf16 3-pass: S = Qh*Kh + Qh*Kl + Ql*Kh).
// Scalar-FMA variants plateaued at 57-73 us with VALUBusy ~= pure-FMA floor;
// MFMA makes compute trivial -> HBM-bound. Transpose to [c][hw] bf16 during
// LDS staging with G4 XOR swizzle so every fragment read is one ds_read_b128
// with even bank load. Each wave owns a 16q x 64k strip over ALL block hw
// (no cross-wave reduction). Softmax/out unchanged (round-6 proven).

typedef __attribute__((ext_vector_type(8))) short bf16x8;
typedef __attribute__((ext_vector_type(4))) float f32x4;

__device__ __forceinline__ unsigned short f2bf(float x) {   // RNE float->bf16
  unsigned u = __builtin_bit_cast(unsigned, x);
  u += 0x7FFFu + ((u >> 16) & 1u);
  return (unsigned short)(u >> 16);
}
__device__ __forceinline__ float bf2f(unsigned short h) {
  unsigned u = (unsigned)h << 16;
  return __builtin_bit_cast(float, u);
}

// ---------------- Kernel A: partial scores via MFMA 16x16x32 bf16, split-bf16 3-pass ----------------
// Block: 256 thr = 4 waves; 64-hw tiles staged transposed+converted into LDS:
// T[buf][arr][c][hw] bf16 (arr: Qh,Ql,Kh,Kl), swizzled elem hw' = hw ^ ((c&7)<<3).
// Wave w computes q-strip w*16..w*16+15 x all 64 k, accumulating over the
// block's CH hw rows. A-frag: row q = w*16+(l&15), k-elems (l>>4)*8+j -> one
// b128 read. B-frag: row k-channel, same pattern. D: col=l&15, row=(l>>4)*4+r.
template <int SPLIT>
__global__ __launch_bounds__(256) void scores_kernel(
    const float* __restrict__ Q, const float* __restrict__ K,
    float* __restrict__ partial) {
  constexpr int CH = 16384 / SPLIT;       // hw rows per split chunk
  constexpr int NTT = CH / 64;            // 64-hw tiles
  const int bs = blockIdx.x;              // b * SPLIT + s
  const int b = bs / SPLIT;
  const int s = bs % SPLIT;
  const int tid = threadIdx.x;
  const int w = tid >> 6;                 // wave 0..3
  const int l = tid & 63;

  __shared__ unsigned short T[2][4][64][64];   // 64 KB: [buf][Qh,Ql,Kh,Kl][c][hw]

  const float4* Qg = (const float4*)(Q + ((size_t)b * 16384 + (size_t)s * CH) * 64);
  const float4* Kg = (const float4*)(K + ((size_t)b * 16384 + (size_t)s * CH) * 64);

  // staging tasks: threads 0..127 stage Q, 128..255 stage K.
  // task (c4, hq): global rows hw = 4*hq..4*hq+3, cols 4*c4..4*c4+3.
  const int half = tid >> 7;                   // 0: Q, 1: K
  const int c4 = tid & 15;
  const int hq0 = (tid >> 4) & 7;              // tasks hq0 and hq0+8
  const float4* Sg = half ? Kg : Qg;
  const int arrH = half ? 2 : 0, arrL = half ? 3 : 1;

  auto stage_load = [&](int t, int hq, float4& r0, float4& r1, float4& r2, float4& r3) {
    const float4* src = Sg + (size_t)(t * 64 + 4 * hq) * 16 + c4;
    r0 = src[0]; r1 = src[16]; r2 = src[32]; r3 = src[48];
  };
  auto stage_write = [&](int buf, int hq, float4 r0, float4 r1, float4 r2, float4 r3) {
    const float* p0 = (const float*)&r0; const float* p1 = (const float*)&r1;
    const float* p2 = (const float*)&r2; const float* p3 = (const float*)&r3;
#pragma unroll
    for (int j = 0; j < 4; ++j) {
      const int c = 4 * c4 + j;
      const float v0 = p0[j], v1 = p1[j], v2 = p2[j], v3 = p3[j];
      const unsigned short h0 = f2bf(v0), h1 = f2bf(v1), h2 = f2bf(v2), h3 = f2bf(v3);
      const unsigned short g0 = f2bf(v0 - bf2f(h0)), g1 = f2bf(v1 - bf2f(h1));
      const unsigned short g2 = f2bf(v2 - bf2f(h2)), g3 = f2bf(v3 - bf2f(h3));
      const int hqs = hq ^ ((c & 7) << 1);       // swizzled hw-quad index
      *(uint2*)&T[buf][arrH][c][4 * hqs] =
          make_uint2((unsigned)h0 | ((unsigned)h1 << 16), (unsigned)h2 | ((unsigned)h3 << 16));
      *(uint2*)&T[buf][arrL][c][4 * hqs] =
          make_uint2((unsigned)g0 | ((unsigned)g1 << 16), (unsigned)g2 | ((unsigned)g3 << 16));
    }
  };
  // fragment read: row r of array arr, k-elements step*32 + (l>>4)*8 .. +7
  auto frag = [&](int buf, int arr, int row, int step) -> bf16x8 {
    const int e = (step * 32 + ((l >> 4) << 3)) ^ ((row & 7) << 3);
    return *(const bf16x8*)&T[buf][arr][row][e];
  };

  f32x4 acc[4] = {};                      // 4 k-tiles x 4 rows

  // prologue: stage tile 0 into buf 0
  {
    float4 a0, a1, a2, a3, b0, b1, b2, b3;
    stage_load(0, hq0, a0, a1, a2, a3);
    stage_load(0, hq0 + 8, b0, b1, b2, b3);
    stage_write(0, hq0, a0, a1, a2, a3);
    stage_write(0, hq0 + 8, b0, b1, b2, b3);
  }

  const int arow = w * 16 + (l & 15);     // this wave's A row (q)
  const int bcol = l & 15;

  for (int t = 0; t < NTT; ++t) {
    __syncthreads();                      // buf (t&1) staged; other buf free
    const int cb = t & 1;

    float4 a0, a1, a2, a3, b0, b1, b2, b3;
    if (t + 1 < NTT) {                    // issue next tile's loads (hide under MFMA)
      stage_load(t + 1, hq0, a0, a1, a2, a3);
      stage_load(t + 1, hq0 + 8, b0, b1, b2, b3);
    }

#pragma unroll
    for (int step = 0; step < 2; ++step) {
      const bf16x8 ah = frag(cb, 0, arow, step);
      const bf16x8 al = frag(cb, 1, arow, step);
#pragma unroll
      for (int kt = 0; kt < 4; ++kt) {
        const bf16x8 bh = frag(cb, 2, kt * 16 + bcol, step);
        const bf16x8 bl = frag(cb, 3, kt * 16 + bcol, step);
        acc[kt] = __builtin_amdgcn_mfma_f32_16x16x32_bf16(ah, bh, acc[kt], 0, 0, 0);
        acc[kt] = __builtin_amdgcn_mfma_f32_16x16x32_bf16(ah, bl, acc[kt], 0, 0, 0);
        acc[kt] = __builtin_amdgcn_mfma_f32_16x16x32_bf16(al, bh, acc[kt], 0, 0, 0);
      }
    }

    if (t + 1 < NTT) {                    // convert + write into the other buffer
      const int nb = (t + 1) & 1;
      stage_write(nb, hq0, a0, a1, a2, a3);
      stage_write(nb, hq0 + 8, b0, b1, b2, b3);
    }
  }

  // store partial: D col = l&15 (k), row = (l>>4)*4 + r (q within strip)
  float* P = partial + (size_t)bs * 4096;
#pragma unroll
  for (int kt = 0; kt < 4; ++kt) {
#pragma unroll
    for (int r = 0; r < 4; ++r) {
      const int q = w * 16 + ((l >> 4) << 2) + r;
      P[q * 64 + kt * 16 + (l & 15)] = acc[kt][r];
    }
  }
}

// ---------------- Kernel B: reduce partials + softmax, store TRANSPOSED attn_t[b][k][q] ----------------
// Block = (b, q-quad), 4 waves: wave w sums splits {w, w+4, ...}; 4-way LDS
// combine; wave 0 does the 16-lane shuffle softmax + transposed store.
template <int SPLIT>
__global__ __launch_bounds__(256) void softmax_kernel(
    const float* __restrict__ partial, float* __restrict__ attn_t) {
  const int blk = blockIdx.x;           // b*16 + qquad
  const int b = blk >> 4;
  const int q0 = (blk & 15) * 4;
  const int tid = threadIdx.x;
  const int w = tid >> 6;
  const int l = tid & 63;
  const int ql = l >> 4;                // q = q0+ql
  const int k4 = l & 15;                // float4 column

  __shared__ float4 red4[4][64];        // 4 KB

  const float4* P = (const float4*)partial;
  float4 v = make_float4(0.f, 0.f, 0.f, 0.f);
  for (int s = w; s < SPLIT; s += 4) {
    float4 t = P[((size_t)(b * SPLIT + s) * 64 + q0 + ql) * 16 + k4];
    v.x += t.x; v.y += t.y; v.z += t.z; v.w += t.w;
  }
  red4[w][l] = v;
  __syncthreads();
  if (w != 0) return;

  float4 v1 = red4[1][l], v2 = red4[2][l], v3 = red4[3][l];
  v.x += v1.x + v2.x + v3.x;
  v.y += v1.y + v2.y + v3.y;
  v.z += v1.z + v2.z + v3.z;
  v.w += v1.w + v2.w + v3.w;

  float m = fmaxf(fmaxf(v.x, v.y), fmaxf(v.z, v.w));
#pragma unroll
  for (int off = 8; off > 0; off >>= 1)
    m = fmaxf(m, __shfl_xor(m, off, 64));   // reduce across the 16 lanes sharing q
  float4 e = make_float4(__expf(v.x - m), __expf(v.y - m), __expf(v.z - m), __expf(v.w - m));
  float sum = e.x + e.y + e.z + e.w;
#pragma unroll
  for (int off = 8; off > 0; off >>= 1)
    sum += __shfl_xor(sum, off, 64);
  const float inv = 1.f / sum;

  float* A = attn_t + (size_t)b * 4096;   // [k][q]
  A[(4 * k4 + 0) * 64 + q0 + ql] = e.x * inv;
  A[(4 * k4 + 1) * 64 + q0 + ql] = e.y * inv;
  A[(4 * k4 + 2) * 64 + q0 + ql] = e.z * inv;
  A[(4 * k4 + 3) * 64 + q0 + ql] = e.w * inv;
}

// ---------------- Kernel C: out = V * attn_t, 8x8 lane tile, XOR-swizzled V (no pad) ----------------
// PROVEN round-6. Block = 256 rows x 64 q, 4 waves; wave w owns rows
// w*64..w*64+63. Lane (rg=l>>3, qg=l&7): rows {rg+8i}, q cols {4qg..4qg+3}
// u {32+4qg..35+4qg}. V LDS quad index = row*16 + (k4 ^ (row&7)): 8 rg-rows
// hit 8 distinct bank-quads (T2, zero pad): V 64 KB + A 16 KB = 80 KB =
// 2 blocks/CU. 16 b128 reads / 256 FMAs per k4 per wave. One barrier total.
__global__ __launch_bounds__(256) void out_kernel(
    const float* __restrict__ V, const float* __restrict__ attn_t,
    float* __restrict__ out) {
  const int b = blockIdx.x >> 6;        // 64 tiles of 256 rows per batch
  const int tile = blockIdx.x & 63;
  const int tid = threadIdx.x;
  const int w = tid >> 6;
  const int l = tid & 63;
  const int rg = l >> 3;                // 0..7
  const int qg = l & 7;                 // 0..7

  __shared__ float4 Vl[256 * 16];       // swizzled, 64 KB
  __shared__ float4 Al[64 * 16];        // attn_t[k][q] row-major, 16 KB

  const float4* Vg = (const float4*)(V + ((size_t)b * 16384 + (size_t)tile * 256) * 64);
#pragma unroll
  for (int u = 0; u < 16; ++u) {
    const int n = u * 256 + tid;        // linear quad 0..4095 of the 256x64 tile
    const int r = n >> 4, c = n & 15;
    Vl[(r << 4) | (c ^ (r & 7))] = Vg[n];
  }
  const float4* Ag = (const float4*)(attn_t + (size_t)b * 4096);
#pragma unroll
  for (int u = 0; u < 4; ++u)
    Al[u * 256 + tid] = Ag[u * 256 + tid];
  __syncthreads();

  float acc[8][8];
#pragma unroll
  for (int i = 0; i < 8; ++i)
#pragma unroll
    for (int j = 0; j < 8; ++j) acc[i][j] = 0.f;

#pragma unroll 2
  for (int k4 = 0; k4 < 16; ++k4) {
    float4 alo[4], ahi[4];
#pragma unroll
    for (int j = 0; j < 4; ++j) {
      alo[j] = Al[(4 * k4 + j) * 16 + qg];        // A[4k4+j][4qg..4qg+3]
      ahi[j] = Al[(4 * k4 + j) * 16 + 8 + qg];    // A[4k4+j][32+4qg..35+4qg]
    }
#pragma unroll
    for (int i = 0; i < 8; ++i) {
      const int row = (w << 6) + rg + 8 * i;      // row&7 == rg
      const float4 v = Vl[(row << 4) | (k4 ^ rg)];// V[row][4k4..4k4+3]
      acc[i][0] += v.x * alo[0].x + v.y * alo[1].x + v.z * alo[2].x + v.w * alo[3].x;
      acc[i][1] += v.x * alo[0].y + v.y * alo[1].y + v.z * alo[2].y + v.w * alo[3].y;
      acc[i][2] += v.x * alo[0].z + v.y * alo[1].z + v.z * alo[2].z + v.w * alo[3].z;
      acc[i][3] += v.x * alo[0].w + v.y * alo[1].w + v.z * alo[2].w + v.w * alo[3].w;
      acc[i][4] += v.x * ahi[0].x + v.y * ahi[1].x + v.z * ahi[2].x + v.w * ahi[3].x;
      acc[i][5] += v.x * ahi[0].y + v.y * ahi[1].y + v.z * ahi[2].y + v.w * ahi[3].y;
      acc[i][6] += v.x * ahi[0].z + v.y * ahi[1].z + v.z * ahi[2].z + v.w * ahi[3].z;
      acc[i][7] += v.x * ahi[0].w + v.y * ahi[1].w + v.z * ahi[2].w + v.w * ahi[3].w;
    }
  }

  float4* og = (float4*)(out + ((size_t)b * 16384 + (size_t)tile * 256) * 64);
#pragma unroll
  for (int i = 0; i < 8; ++i) {
    const int row = (w << 6) + rg + 8 * i;
    og[row * 16 + qg]     = make_float4(acc[i][0], acc[i][1], acc[i][2], acc[i][3]);
    og[row * 16 + 8 + qg] = make_float4(acc[i][4], acc[i][5], acc[i][6], acc[i][7]);
  }
}

extern "C" void kernel_launch(void* const* d_in, const int* in_sizes, int n_in,
                              void* d_out, int out_size, void* d_ws, size_t ws_size,
                              hipStream_t stream) {
  const float* Q = (const float*)d_in[0];
  const float* K = (const float*)d_in[1];
  const float* V = (const float*)d_in[2];
  float* out = (float*)d_out;

  const size_t need64 = (size_t)16 * 64 * 4096 * 4 + (size_t)16 * 4096 * 4;  // 16 MiB + 256 KiB

  if (ws_size >= need64) {
    float* partial = (float*)d_ws;
    float* attn_t = partial + (size_t)16 * 64 * 4096;
    scores_kernel<64><<<16 * 64, 256, 0, stream>>>(Q, K, partial);
    softmax_kernel<64><<<16 * 16, 256, 0, stream>>>(partial, attn_t);
    out_kernel<<<16 * 64, 256, 0, stream>>>(V, attn_t, out);
  } else {
    float* partial = (float*)d_ws;
    float* attn_t = partial + (size_t)16 * 32 * 4096;
    scores_kernel<32><<<16 * 32, 256, 0, stream>>>(Q, K, partial);
    softmax_kernel<32><<<16 * 16, 256, 0, stream>>>(partial, attn_t);
    out_kernel<<<16 * 64, 256, 0, stream>>>(V, attn_t, out);
  }
}